// Round 6
// baseline (1273.882 us; speedup 1.0000x reference)
//
#include <hip/hip_runtime.h>
#include <hip/hip_bf16.h>
#include <math.h>

#define NL   6
#define DM   768
#define NH   8
#define DQ   96
#define DFF  3072
#define BB   8
#define TT   512
#define NTOK (BB*TT)      // 4096 tokens
#define NREL 201
#define WIN  99
#define ODIM 80
#define NQKV 2304         // fused q|k|v columns
#define RELD 208          // padded e-dim of REL buffer

typedef __attribute__((ext_vector_type(8))) short v8s;
typedef __attribute__((ext_vector_type(4))) float v4f;
typedef __attribute__((ext_vector_type(16))) float v16f;

static __device__ __forceinline__ short bf16bits(float x) {
  __hip_bfloat16 h = __float2bfloat16(x);
  return *(short*)&h;
}
static __device__ __forceinline__ unsigned short bf16u(float x) {
  __hip_bfloat16 h = __float2bfloat16(x);
  return *(unsigned short*)&h;
}

// ---------------- input transpose: x(B,T,D) -> src(token n=t*8+b, D) fp32 + bf16 ----------------
__global__ void k_transpose_in(const float* __restrict__ x, float* __restrict__ src,
                               __hip_bfloat16* __restrict__ srcb) {
  int n = blockIdx.x;               // n = t*8 + b
  int t = n >> 3, b = n & 7;
  const float* xi = x + ((size_t)b*TT + t)*DM;
  for (int d = threadIdx.x; d < DM; d += blockDim.x) {
    float v = xi[d];
    src[(size_t)n*DM + d] = v;
    srcb[(size_t)n*DM + d] = __float2bfloat16(v);
  }
}

// ---------------- LDS-tiled weight transposes (coalesced both sides) ----------------
__global__ __launch_bounds__(256)
void k_conv_qkvw(const float* __restrict__ wq, const float* __restrict__ wk,
                 const float* __restrict__ wv, __hip_bfloat16* __restrict__ o) {
  __shared__ float tile[64][33];
  const int ft = blockIdx.x, at = blockIdx.y;
  const int l = blockIdx.z >> 3, h = blockIdx.z & 7;
  const int f0 = ft*64, a0 = at*32;
  const int tx = threadIdx.x & 31, ty = threadIdx.x >> 5;
  const float* srcs[3] = {wq, wk, wv};
  #pragma unroll
  for (int part = 0; part < 3; ++part) {
    const float* s = srcs[part] + (size_t)l*DM*DM + (size_t)h*DM*DQ;   // [f][a]
    #pragma unroll
    for (int p = 0; p < 8; ++p)
      tile[ty + 8*p][tx] = s[(size_t)(f0 + ty + 8*p)*DQ + (a0 + tx)];
    __syncthreads();
    const float sc = (part == 0) ? 0.10206207261596577f : 1.f;
    unsigned short* d = (unsigned short*)o + (size_t)l*NQKV*DM + (size_t)(part*DM + h*DQ)*DM;
    #pragma unroll
    for (int p = 0; p < 4; ++p) {
      int a = ty + 8*p;
      int f = 2*tx;
      ushort2 pr = make_ushort2(bf16u(tile[f][a]*sc), bf16u(tile[f+1][a]*sc));
      *(ushort2*)(d + (size_t)(a0 + a)*DM + f0 + f) = pr;
    }
    __syncthreads();
  }
}

__global__ __launch_bounds__(256)
void k_conv_wo(const float* __restrict__ wo, __hip_bfloat16* __restrict__ o) {
  __shared__ float tile[64][33];
  const int rt = blockIdx.x, dt = blockIdx.y, l = blockIdx.z;
  const int r0 = rt*64, d0 = dt*32;
  const int tx = threadIdx.x & 31, ty = threadIdx.x >> 5;
  const float* s = wo + (size_t)l*DM*DM;
  #pragma unroll
  for (int p = 0; p < 8; ++p)
    tile[ty + 8*p][tx] = s[(size_t)(r0 + ty + 8*p)*DM + d0 + tx];
  __syncthreads();
  unsigned short* d = (unsigned short*)o + (size_t)l*DM*DM;
  #pragma unroll
  for (int p = 0; p < 4; ++p) {
    int dd = ty + 8*p;
    int r = 2*tx;
    ushort2 pr = make_ushort2(bf16u(tile[r][dd]), bf16u(tile[r+1][dd]));
    *(ushort2*)(d + (size_t)(d0 + dd)*DM + r0 + r) = pr;
  }
}

__global__ void k_cast(const float* __restrict__ in, __hip_bfloat16* __restrict__ o, size_t n) {
  size_t idx = (size_t)blockIdx.x*256 + threadIdx.x;
  if (idx < n) o[idx] = __float2bfloat16(in[idx]);
}

__global__ void k_conv_wout(const float* __restrict__ wout, __hip_bfloat16* __restrict__ o) {
  int idx = blockIdx.x*256 + threadIdx.x;     // over 128*DM
  if (idx >= 128*DM) return;
  int n = idx / DM, f = idx % DM;
  o[idx] = __float2bfloat16(n < ODIM ? wout[(size_t)n*DM + f] : 0.f);
}

// ---------------- 32x32x16-MFMA dbuf GEMM: C[M,N] = A[M,K] * Bt[N,K]^T ----------------
// 4 waves; wave tile WM x WN of 32x32 sub-tiles; BK=64 double-buffered (1 barrier/iter,
// prefetch outstanding across the MFMA phase). M-fastest grid.
// A-frag: row=lane&31, k=(lane>>5)*8+j (generalization of verified 16x16x32 layout).
// C/D:    col=lane&31, row=(reg&3)+8*(reg>>2)+4*(lane>>5)  [m74/m101-verified]
template<int BM, int BN, int WM, int WN, bool RELU, bool BF16OUT>
__global__ __launch_bounds__(256)
void k_gemm32(const __hip_bfloat16* __restrict__ A, const __hip_bfloat16* __restrict__ Bt,
              const float* __restrict__ bias, void* __restrict__ Cv,
              int K, int ldc) {
  constexpr int NWN = BN/WN;
  constexpr int FM = WM/32, FN = WN/32;
  __shared__ __align__(16) short As[2][BM*64];
  __shared__ __align__(16) short Bs[2][BN*64];
  const int tid = threadIdx.x;
  const int m0 = blockIdx.x*BM, n0 = blockIdx.y*BN;
  const int lane = tid & 63, w = tid >> 6;
  const int wm = (w / NWN)*WM, wn = (w % NWN)*WN;
  const int r31 = lane & 31, h = lane >> 5;
  const short* Ag = (const short*)A;
  const short* Bg = (const short*)Bt;
  v16f acc[FM][FN];
  #pragma unroll
  for (int i=0;i<FM;++i)
    #pragma unroll
    for (int j=0;j<FN;++j)
      #pragma unroll
      for (int r=0;r<16;++r) acc[i][j][r] = 0.f;

  auto stage = [&](int k0, int buf) {
    #pragma unroll
    for (int s = 0; s < (BM*8)/256; ++s) {
      int cid = s*256 + tid;
      int row = cid >> 3;
      int c = (cid & 7) ^ (row & 7);
      __builtin_amdgcn_global_load_lds(
        (const __attribute__((address_space(1))) void*)(Ag + (size_t)(m0+row)*K + k0 + c*8),
        (__attribute__((address_space(3))) void*)(&As[buf][cid*8]), 16, 0, 0);
    }
    #pragma unroll
    for (int s = 0; s < (BN*8)/256; ++s) {
      int cid = s*256 + tid;
      int row = cid >> 3;
      int c = (cid & 7) ^ (row & 7);
      __builtin_amdgcn_global_load_lds(
        (const __attribute__((address_space(1))) void*)(Bg + (size_t)(n0+row)*K + k0 + c*8),
        (__attribute__((address_space(3))) void*)(&Bs[buf][cid*8]), 16, 0, 0);
    }
  };

  const int nk = K >> 6;
  stage(0, 0);
  for (int it = 0; it < nk; ++it) {
    __syncthreads();                 // drains tile-it loads (issued a full compute phase ago)
    if (it + 1 < nk) stage((it+1)*64, (it+1)&1);
    const short* Ab = As[it&1];
    const short* Bb = Bs[it&1];
    #pragma unroll
    for (int ks = 0; ks < 4; ++ks) {
      v8s af[FM], bf[FN];
      #pragma unroll
      for (int i=0;i<FM;++i) {
        int r = wm + i*32 + r31;
        af[i] = *(const v8s*)(Ab + r*64 + (((ks<<1)|h) ^ (r&7))*8);
      }
      #pragma unroll
      for (int j=0;j<FN;++j) {
        int r = wn + j*32 + r31;
        bf[j] = *(const v8s*)(Bb + r*64 + (((ks<<1)|h) ^ (r&7))*8);
      }
      #pragma unroll
      for (int i=0;i<FM;++i)
        #pragma unroll
        for (int j=0;j<FN;++j)
          acc[i][j] = __builtin_amdgcn_mfma_f32_32x32x16_bf16(af[i], bf[j], acc[i][j], 0, 0, 0);
    }
  }

  #pragma unroll
  for (int j=0;j<FN;++j) {
    int col = n0 + wn + j*32 + r31;
    float bv = bias ? bias[col] : 0.f;
    #pragma unroll
    for (int i=0;i<FM;++i) {
      #pragma unroll
      for (int r=0;r<16;++r) {
        int m = m0 + wm + i*32 + (r&3) + 8*(r>>2) + 4*h;
        float val = acc[i][j][r] + bv;
        if (RELU) val = fmaxf(val, 0.f);
        if (BF16OUT) ((__hip_bfloat16*)Cv)[(size_t)m*ldc + col] = __float2bfloat16(val);
        else         ((float*)Cv)[(size_t)m*ldc + col] = val;
      }
    }
  }
}

// ---------------- 16x16x32 dbuf GEMM (kept for out-proj: PERM epilogue + Nvalid mask) ----------------
template<int BM, int BN, int WM, int WN, bool RELU, bool BF16OUT, bool PERM>
__global__ __launch_bounds__(256)
void k_mfma_gemm(const __hip_bfloat16* __restrict__ A, const __hip_bfloat16* __restrict__ Bt,
                 const float* __restrict__ bias, void* __restrict__ Cv,
                 int K, int Nvalid, int ldc) {
  constexpr int NWN = BN/WN;
  constexpr int FM = WM/16, FN = WN/16;
  __shared__ __align__(16) short As[2][BM*64];
  __shared__ __align__(16) short Bs[2][BN*64];
  const int tid = threadIdx.x;
  const int m0 = blockIdx.x*BM, n0 = blockIdx.y*BN;
  const int lane = tid & 63, w = tid >> 6;
  const int wm = (w / NWN)*WM, wn = (w % NWN)*WN;
  const int mr = lane & 15, q4 = lane >> 4;
  const short* Ag = (const short*)A;
  const short* Bg = (const short*)Bt;
  const v4f zero = {0.f, 0.f, 0.f, 0.f};
  v4f acc[FM][FN];
  #pragma unroll
  for (int i=0;i<FM;++i)
    #pragma unroll
    for (int j=0;j<FN;++j) acc[i][j] = zero;

  auto stage = [&](int k0, int buf) {
    #pragma unroll
    for (int s = 0; s < (BM*8)/256; ++s) {
      int cid = s*256 + tid;
      int row = cid >> 3;
      int c = (cid & 7) ^ (row & 7);
      __builtin_amdgcn_global_load_lds(
        (const __attribute__((address_space(1))) void*)(Ag + (size_t)(m0+row)*K + k0 + c*8),
        (__attribute__((address_space(3))) void*)(&As[buf][cid*8]), 16, 0, 0);
    }
    #pragma unroll
    for (int s = 0; s < (BN*8)/256; ++s) {
      int cid = s*256 + tid;
      int row = cid >> 3;
      int c = (cid & 7) ^ (row & 7);
      __builtin_amdgcn_global_load_lds(
        (const __attribute__((address_space(1))) void*)(Bg + (size_t)(n0+row)*K + k0 + c*8),
        (__attribute__((address_space(3))) void*)(&Bs[buf][cid*8]), 16, 0, 0);
    }
  };

  const int nk = K >> 6;
  stage(0, 0);
  for (int it = 0; it < nk; ++it) {
    __syncthreads();
    if (it + 1 < nk) stage((it+1)*64, (it+1)&1);
    const short* Ab = As[it&1];
    const short* Bb = Bs[it&1];
    #pragma unroll
    for (int kh = 0; kh < 2; ++kh) {
      int pos = (kh*4 + q4) ^ (mr & 7);
      v8s af[FM], bf[FN];
      #pragma unroll
      for (int ii=0;ii<FM;++ii) af[ii] = *(const v8s*)(Ab + (wm + ii*16 + mr)*64 + pos*8);
      #pragma unroll
      for (int j=0;j<FN;++j) bf[j] = *(const v8s*)(Bb + (wn + j*16 + mr)*64 + pos*8);
      #pragma unroll
      for (int ii=0;ii<FM;++ii)
        #pragma unroll
        for (int j=0;j<FN;++j)
          acc[ii][j] = __builtin_amdgcn_mfma_f32_16x16x32_bf16(af[ii], bf[j], acc[ii][j], 0, 0, 0);
    }
  }

  #pragma unroll
  for (int j=0;j<FN;++j) {
    int col = n0 + wn + j*16 + mr;
    if (col < Nvalid) {
      float bv = bias ? bias[col] : 0.f;
      #pragma unroll
      for (int i=0;i<FM;++i) {
        #pragma unroll
        for (int r=0;r<4;++r) {
          int m = m0 + wm + i*16 + q4*4 + r;
          float val = acc[i][j][r] + bv;
          if (RELU) val = fmaxf(val, 0.f);
          int row = PERM ? ((m & 7)*TT + (m >> 3)) : m;   // token t*8+b -> b*512+t
          if (BF16OUT) ((__hip_bfloat16*)Cv)[(size_t)row*ldc + col] = __float2bfloat16(val);
          else         ((float*)Cv)[(size_t)row*ldc + col] = val;
        }
      }
    }
  }
}

// ---------------- REL precompute: REL[h][n][e] = q_n . emb_h[e], fp32 out ----------------
__global__ __launch_bounds__(256)
void k_rel_gemm(const __hip_bfloat16* __restrict__ qkvb,
                const __hip_bfloat16* __restrict__ embb,
                float* __restrict__ rel) {
  const int e0 = blockIdx.x*64, m0 = blockIdx.y*64, h = blockIdx.z;
  const int tid = threadIdx.x, lane = tid & 63, w = tid >> 6;
  const int l15 = lane & 15, q4 = lane >> 4;
  __shared__ __align__(16) short As[64*104];
  __shared__ __align__(16) short Bs[64*104];
  const short* qg = (const short*)qkvb;
  const short* eg = (const short*)embb;
  {
    int row = tid >> 2;
    const short* sa = qg + (size_t)(m0+row)*NQKV + h*DQ;
    int er = e0 + row; if (er > 200) er = 200;
    const short* sb = eg + ((size_t)h*NREL + er)*DQ;
    short* da = As + row*104;
    short* db = Bs + row*104;
    #pragma unroll
    for (int c = 0; c < 3; ++c) {
      int ch = (tid & 3)*3 + c;
      *(v8s*)(da + ch*8) = *(const v8s*)(sa + ch*8);
      *(v8s*)(db + ch*8) = *(const v8s*)(sb + ch*8);
    }
  }
  __syncthreads();
  const v4f zero = {0.f,0.f,0.f,0.f};
  v4f acc[4] = {zero, zero, zero, zero};
  #pragma unroll
  for (int ks = 0; ks < 3; ++ks) {
    v8s af = *(const v8s*)(As + (w*16 + l15)*104 + ks*32 + q4*8);
    #pragma unroll
    for (int f = 0; f < 4; ++f) {
      v8s bf = *(const v8s*)(Bs + (f*16 + l15)*104 + ks*32 + q4*8);
      acc[f] = __builtin_amdgcn_mfma_f32_16x16x32_bf16(af, bf, acc[f], 0, 0, 0);
    }
  }
  #pragma unroll
  for (int f = 0; f < 4; ++f) {
    int e = e0 + f*16 + l15;
    if (e < 2*WIN + 1) {
      #pragma unroll
      for (int r = 0; r < 4; ++r) {
        int n = m0 + w*16 + q4*4 + r;
        rel[((size_t)h*NTOK + n)*RELD + e] = acc[f][r];
      }
    }
  }
}

// ---------------- banded MFMA attention ----------------
__global__ __launch_bounds__(256)
void k_attn_mfma(const __hip_bfloat16* __restrict__ qkvb,
                 const float* __restrict__ rel,
                 __hip_bfloat16* __restrict__ o) {
  const int qt = blockIdx.x, h = blockIdx.y, b = blockIdx.z;
  const int qlo = qt*64;
  const int tid = threadIdx.x, lane = tid & 63, w = tid >> 6;
  const int l15 = lane & 15, q4 = lane >> 4;
  __shared__ __align__(16) short Qs[64*104];
  __shared__ __align__(16) short Ks[64*104];
  __shared__ __align__(16) short Vt[96*72];
  __shared__ __align__(16) short Ps[64*72];
  const short* qg = (const short*)qkvb;

  {
    int row = tid >> 2;
    const short* src = qg + (size_t)((qlo+row)*8 + b)*NQKV + h*DQ;
    short* dst = Qs + row*104;
    #pragma unroll
    for (int c = 0; c < 3; ++c) {
      int ch = (tid & 3)*3 + c;
      *(v8s*)(dst + ch*8) = *(const v8s*)(src + ch*8);
    }
  }

  v4f sacc[5][4];
  const v4f neg = {-1e30f,-1e30f,-1e30f,-1e30f};
  #pragma unroll
  for (int kt=0;kt<5;++kt)
    #pragma unroll
    for (int f=0;f<4;++f) sacc[kt][f] = neg;

  const int i_row0 = qlo + w*16 + q4*4;   // + r

  // ---- phase 1: S = QK^T + REL ----
  for (int kt = 0; kt < 5; ++kt) {
    int kt0 = qlo + kt*64 - 128;
    if (kt0 + 64 <= 0 || kt0 >= TT) continue;
    {
      int row = tid >> 2;
      int j = kt0 + row; j = j < 0 ? 0 : (j > TT-1 ? TT-1 : j);
      const short* src = qg + (size_t)(j*8 + b)*NQKV + DM + h*DQ;
      short* dst = Ks + row*104;
      #pragma unroll
      for (int c = 0; c < 3; ++c) {
        int ch = (tid & 3)*3 + c;
        *(v8s*)(dst + ch*8) = *(const v8s*)(src + ch*8);
      }
    }
    __syncthreads();
    #pragma unroll
    for (int f = 0; f < 4; ++f) {
      int j = kt0 + f*16 + l15;
      #pragma unroll
      for (int r = 0; r < 4; ++r) {
        int i = i_row0 + r;
        int d = j - i;
        float val = -1e30f;
        if (j >= 0 && j < TT && d >= -WIN && d <= WIN)
          val = rel[((size_t)h*NTOK + i*8 + b)*RELD + d + WIN];
        sacc[kt][f][r] = val;
      }
    }
    #pragma unroll
    for (int ks = 0; ks < 3; ++ks) {
      v8s af = *(const v8s*)(Qs + (w*16 + l15)*104 + ks*32 + q4*8);
      #pragma unroll
      for (int f = 0; f < 4; ++f) {
        v8s bf = *(const v8s*)(Ks + (f*16 + l15)*104 + ks*32 + q4*8);
        sacc[kt][f] = __builtin_amdgcn_mfma_f32_16x16x32_bf16(af, bf, sacc[kt][f], 0, 0, 0);
      }
    }
    __syncthreads();
  }

  // ---- phase 2: softmax in registers ----
  float inv[4];
  #pragma unroll
  for (int r = 0; r < 4; ++r) {
    float m = -1e30f;
    #pragma unroll
    for (int kt=0;kt<5;++kt)
      #pragma unroll
      for (int f=0;f<4;++f) m = fmaxf(m, sacc[kt][f][r]);
    #pragma unroll
    for (int off=1; off<16; off<<=1) m = fmaxf(m, __shfl_xor(m, off));
    float l = 0.f;
    #pragma unroll
    for (int kt=0;kt<5;++kt)
      #pragma unroll
      for (int f=0;f<4;++f) {
        float p = __expf(sacc[kt][f][r] - m);
        sacc[kt][f][r] = p; l += p;
      }
    #pragma unroll
    for (int off=1; off<16; off<<=1) l += __shfl_xor(l, off);
    inv[r] = 1.f / l;
  }

  // ---- phase 3: O = P V ----
  v4f oacc[6];
  const v4f zero = {0.f,0.f,0.f,0.f};
  #pragma unroll
  for (int f=0;f<6;++f) oacc[f] = zero;
  for (int kt = 0; kt < 5; ++kt) {
    int kt0 = qlo + kt*64 - 128;
    if (kt0 + 64 <= 0 || kt0 >= TT) continue;
    #pragma unroll
    for (int f=0;f<4;++f)
      #pragma unroll
      for (int r=0;r<4;++r)
        Ps[(w*16 + q4*4 + r)*72 + f*16 + l15] = bf16bits(sacc[kt][f][r]);
    {
      int j = kt0 + (tid >> 2);
      int jc = j < 0 ? 0 : (j > TT-1 ? TT-1 : j);
      const short* src = qg + (size_t)(jc*8 + b)*NQKV + 2*DM + h*DQ + (tid & 3)*24;
      union { v8s v[3]; short s[24]; } u;
      u.v[0] = *(const v8s*)(src);
      u.v[1] = *(const v8s*)(src + 8);
      u.v[2] = *(const v8s*)(src + 16);
      int a0 = (tid & 3)*24, jl = tid >> 2;
      #pragma unroll
      for (int t=0;t<24;++t) Vt[(a0+t)*72 + jl] = u.s[t];
    }
    __syncthreads();
    #pragma unroll
    for (int ks=0;ks<2;++ks) {
      v8s af = *(const v8s*)(Ps + (w*16 + l15)*72 + ks*32 + q4*8);
      #pragma unroll
      for (int f=0;f<6;++f) {
        v8s bf = *(const v8s*)(Vt + (f*16 + l15)*72 + ks*32 + q4*8);
        oacc[f] = __builtin_amdgcn_mfma_f32_16x16x32_bf16(af, bf, oacc[f], 0, 0, 0);
      }
    }
    __syncthreads();
  }

  #pragma unroll
  for (int f=0;f<6;++f)
    #pragma unroll
    for (int r=0;r<4;++r) {
      int i = i_row0 + r;
      o[(size_t)(i*8 + b)*DM + h*DQ + f*16 + l15] = __float2bfloat16(oacc[f][r] * inv[r]);
    }
}

// ---------------- fused residual + LayerNorm (in-place on src, + bf16 copy) ----------------
__global__ __launch_bounds__(256)
void k_ln_residual(float* __restrict__ src, const float* __restrict__ res,
                   const float* __restrict__ g, const float* __restrict__ bta,
                   __hip_bfloat16* __restrict__ srcb) {
  __shared__ float red[4];
  int n = blockIdx.x;
  float x[3];
  float s = 0.f;
  #pragma unroll
  for (int u=0;u<3;++u) {
    int d = u*256 + threadIdx.x;
    x[u] = src[(size_t)n*DM + d] + res[(size_t)n*DM + d];
    s += x[u];
  }
  #pragma unroll
  for (int off=32; off; off>>=1) s += __shfl_xor(s, off);
  if ((threadIdx.x & 63) == 0) red[threadIdx.x>>6] = s;
  __syncthreads();
  float mu = (red[0]+red[1]+red[2]+red[3]) * (1.f/DM);
  __syncthreads();
  float vs = 0.f;
  #pragma unroll
  for (int u=0;u<3;++u) { float dv = x[u]-mu; vs += dv*dv; }
  #pragma unroll
  for (int off=32; off; off>>=1) vs += __shfl_xor(vs, off);
  if ((threadIdx.x & 63) == 0) red[threadIdx.x>>6] = vs;
  __syncthreads();
  float rstd = rsqrtf((red[0]+red[1]+red[2]+red[3])*(1.f/DM) + 1e-5f);
  #pragma unroll
  for (int u=0;u<3;++u) {
    int d = u*256 + threadIdx.x;
    float v = (x[u]-mu)*rstd*g[d] + bta[d];
    src[(size_t)n*DM + d] = v;
    srcb[(size_t)n*DM + d] = __float2bfloat16(v);
  }
}

extern "C" void kernel_launch(void* const* d_in, const int* in_sizes, int n_in,
                              void* d_out, int out_size, void* d_ws, size_t ws_size,
                              hipStream_t stream) {
  const float* x    = (const float*)d_in[0];
  const float* wq   = (const float*)d_in[1];
  const float* wk   = (const float*)d_in[2];
  const float* wv   = (const float*)d_in[3];
  const float* wo   = (const float*)d_in[4];
  const float* remb = (const float*)d_in[5];
  const float* ff1w = (const float*)d_in[6];
  const float* ff1b = (const float*)d_in[7];
  const float* ff2w = (const float*)d_in[8];
  const float* ff2b = (const float*)d_in[9];
  const float* ln1g = (const float*)d_in[10];
  const float* ln1b = (const float*)d_in[11];
  const float* ln2g = (const float*)d_in[12];
  const float* ln2b = (const float*)d_in[13];
  const float* wout = (const float*)d_in[14];
  const float* bout = (const float*)d_in[15];
  float* out = (float*)d_out;

  float* wsp = (float*)d_ws;
  size_t off = 0;
  float* src  = wsp + off;                              off += (size_t)NTOK*DM;
  __hip_bfloat16* srcb  = (__hip_bfloat16*)(wsp + off); off += (size_t)NTOK*DM/2;
  __hip_bfloat16* qkvb  = (__hip_bfloat16*)(wsp + off); off += (size_t)NTOK*NQKV/2;
  float* rel  = wsp + off;                              off += (size_t)NH*NTOK*RELD;
  float* tmp  = wsp + off;                              off += (size_t)NTOK*DM;
  __hip_bfloat16* qkvwbA = (__hip_bfloat16*)(wsp + off); off += (size_t)NL*NQKV*DM/2;
  __hip_bfloat16* wobA   = (__hip_bfloat16*)(wsp + off); off += (size_t)NL*DM*DM/2;
  __hip_bfloat16* ff1wbA = (__hip_bfloat16*)(wsp + off); off += (size_t)NL*DFF*DM/2;
  __hip_bfloat16* ff2wbA = (__hip_bfloat16*)(wsp + off); off += (size_t)NL*DM*DFF/2;
  __hip_bfloat16* woutb  = (__hip_bfloat16*)(wsp + off); off += (size_t)128*DM/2;
  __hip_bfloat16* embbA  = (__hip_bfloat16*)(wsp + off); off += (size_t)NL*NH*NREL*DQ/2 + 64;
  __hip_bfloat16* hb  = (__hip_bfloat16*)qkvb;  // FF1 out: qkvb(+rel tail) dead post-attention
  __hip_bfloat16* obb = srcb;                   // attention out: srcb dead until LN1 rewrites it
  (void)off; (void)ws_size; (void)in_sizes; (void)n_in; (void)out_size;

  dim3 b256(256);

  // ---- upfront: all weight conversions, batched over layers ----
  k_conv_qkvw<<<dim3(DM/64, DQ/32, NL*NH), b256, 0, stream>>>(wq, wk, wv, qkvwbA);
  k_conv_wo<<<dim3(DM/64, DM/32, NL), b256, 0, stream>>>(wo, wobA);
  k_cast<<<dim3(((size_t)NL*DFF*DM+255)/256), b256, 0, stream>>>(ff1w, ff1wbA, (size_t)NL*DFF*DM);
  k_cast<<<dim3(((size_t)NL*DM*DFF+255)/256), b256, 0, stream>>>(ff2w, ff2wbA, (size_t)NL*DM*DFF);
  k_cast<<<dim3(((size_t)NL*NH*NREL*DQ+255)/256), b256, 0, stream>>>(remb, embbA, (size_t)NL*NH*NREL*DQ);
  k_conv_wout<<<dim3((128*DM+255)/256), b256, 0, stream>>>(wout, woutb);

  k_transpose_in<<<dim3(NTOK), b256, 0, stream>>>(x, src, srcb);

  for (int l = 0; l < NL; ++l) {
    __hip_bfloat16* qkvwb = qkvwbA + (size_t)l*NQKV*DM;
    __hip_bfloat16* wob   = wobA   + (size_t)l*DM*DM;
    __hip_bfloat16* ff1wb = ff1wbA + (size_t)l*DFF*DM;
    __hip_bfloat16* ff2wb = ff2wbA + (size_t)l*DM*DFF;
    __hip_bfloat16* embb  = embbA  + (size_t)l*NH*NREL*DQ;

    // fused QKV (bf16 out): 128x128 dbuf, 32x32 MFMA
    k_gemm32<128,128,64,64,false,true><<<dim3(NTOK/128, NQKV/128), b256, 0, stream>>>(
        srcb, qkvwb, nullptr, qkvb, DM, NQKV);

    // REL[h][n][e] = q . emb
    k_rel_gemm<<<dim3(4, NTOK/64, NH), b256, 0, stream>>>(qkvb, embb, rel);

    // banded MFMA attention
    k_attn_mfma<<<dim3(TT/64, NH, BB), b256, 0, stream>>>(qkvb, rel, obb);

    // O-proj: tmp = obb * wob^T   (64x64 dbuf, 32x32 MFMA, 768 blocks)
    k_gemm32<64,64,32,32,false,false><<<dim3(NTOK/64, DM/64), b256, 0, stream>>>(
        obb, wob, nullptr, tmp, DM, DM);
    k_ln_residual<<<dim3(NTOK), b256, 0, stream>>>(src, tmp, ln1g + (size_t)l*DM, ln1b + (size_t)l*DM, srcb);

    // FF1: hb = relu(srcb * ff1wb^T + b), 128x128 dbuf, 32x32 MFMA
    k_gemm32<128,128,64,64,true,true><<<dim3(NTOK/128, DFF/128), b256, 0, stream>>>(
        srcb, ff1wb, ff1b + (size_t)l*DFF, hb, DM, DFF);
    // FF2: tmp = hb * ff2wb^T + b   (128x64 dbuf, 32x32 MFMA, 384 blocks)
    k_gemm32<128,64,64,32,false,false><<<dim3(NTOK/128, DM/64), b256, 0, stream>>>(
        hb, ff2wb, ff2b + (size_t)l*DM, tmp, DFF, DM);
    k_ln_residual<<<dim3(NTOK), b256, 0, stream>>>(src, tmp, ln2g + (size_t)l*DM, ln2b + (size_t)l*DM, srcb);
  }

  k_mfma_gemm<64,128,64,32,false,false,true><<<dim3(NTOK/64, 1), b256, 0, stream>>>(
      srcb, woutb, bout, out, DM, ODIM, ODIM);
}